// Round 3
// baseline (66.593 us; speedup 1.0000x reference)
//
#include <hip/hip_runtime.h>

// SO3SelfInteraction: y[a,k,f] = sum_e Wcg[e] * x[a,i1[e],f] * x[a,i2[e],f]
// LMAX=2 -> S=9, N_ATOMS=32000, N_FEAT=128.
//
// R2 changes vs R1:
//  - NO LDS in main kernel. x[atom, 0..8, f4] lives in registers (9 x float4).
//  - prep folds the sparse CG into a dense pair-major table W[45][9]
//    ((a<=b) upper-triangle pair x output k, symmetric entries merged) plus a
//    45-bit active-pair mask. Main kernel fully unrolls the 45 pairs
//    (compile-time register indexing), skips inactive pairs via wave-uniform
//    mask bits, and runs all 9 k-FMAs per active pair (zero weights harmless).
//  - y written with nontemporal stores (write-once data; keeps x resident in
//    L3 across graph replays -> fewer HBM fetches).

#define S9 9
#define NFEAT 128
#define THREADS 256
#define NPAIR 45

typedef float f4 __attribute__((ext_vector_type(4)));

// d_ws layout (32-bit words):
//   [0..1] : 64-bit active-pair mask
//   [8..]  : W[45][9] floats (pair-major)

__global__ void so3_prep_kernel(const float* __restrict__ weight,
                                const float* __restrict__ cg_vals,
                                const int* __restrict__ idx_1,
                                const int* __restrict__ idx_2,
                                const int* __restrict__ idx_out,
                                const int* __restrict__ widx_1,
                                const int* __restrict__ widx_2,
                                int nnz, int* __restrict__ ws) {
    __shared__ float d[NPAIR * S9];
    __shared__ unsigned long long smask;
    const int tid = threadIdx.x;

    for (int i = tid; i < NPAIR * S9; i += THREADS) d[i] = 0.f;
    if (tid == 0) smask = 0ull;
    __syncthreads();

    for (int e = tid; e < nnz; e += THREADS) {
        const int i = idx_1[e];
        const int j = idx_2[e];
        const int k = idx_out[e];
        const float w = weight[widx_1[e] * 3 + widx_2[e]] * cg_vals[e];
        const int a = min(i, j);
        const int b = max(i, j);
        const int p = a * 9 - a * (a - 1) / 2 + (b - a);
        // <=2 adds per cell ((i,j) and (j,i)); fp add is commutative -> deterministic
        atomicAdd(&d[p * S9 + k], w);
    }
    __syncthreads();

    if (tid < NPAIR) {
        bool any = false;
        for (int k = 0; k < S9; ++k) any |= (d[tid * S9 + k] != 0.f);
        if (any) atomicOr(&smask, 1ull << tid);
    }
    __syncthreads();

    if (tid == 0) *(unsigned long long*)ws = smask;
    float* W = (float*)(ws + 8);
    for (int i = tid; i < NPAIR * S9; i += THREADS) W[i] = d[i];
}

__global__ __launch_bounds__(THREADS) void so3_main_kernel(
        const float* __restrict__ x,
        const int* __restrict__ ws,
        float* __restrict__ y) {
    const int gid  = blockIdx.x * THREADS + threadIdx.x;
    const int atom = gid >> 5;
    const int c4   = gid & 31;
    const size_t base = (size_t)atom * (S9 * NFEAT) + (size_t)c4 * 4;

    const unsigned long long mask = *(const unsigned long long*)ws;
    const float* __restrict__ W = (const float*)(ws + 8);

    f4 xv[S9];
    #pragma unroll
    for (int s = 0; s < S9; ++s)
        xv[s] = *(const f4*)(x + base + (size_t)s * NFEAT);

    f4 acc[S9];
    #pragma unroll
    for (int k = 0; k < S9; ++k) acc[k] = (f4)0.f;

    #pragma unroll
    for (int a = 0; a < S9; ++a) {
        #pragma unroll
        for (int b = a; b < S9; ++b) {
            const int p = a * 9 - a * (a - 1) / 2 + (b - a);
            if (mask & (1ull << p)) {            // wave-uniform branch
                const f4 prod = xv[a] * xv[b];
                #pragma unroll
                for (int k = 0; k < S9; ++k) {
                    const float w = W[p * S9 + k];   // scalar (s_load) weight
                    acc[k][0] = fmaf(w, prod[0], acc[k][0]);
                    acc[k][1] = fmaf(w, prod[1], acc[k][1]);
                    acc[k][2] = fmaf(w, prod[2], acc[k][2]);
                    acc[k][3] = fmaf(w, prod[3], acc[k][3]);
                }
            }
        }
    }

    #pragma unroll
    for (int k = 0; k < S9; ++k)
        __builtin_nontemporal_store(acc[k], (f4*)(y + base + (size_t)k * NFEAT));
}

extern "C" void kernel_launch(void* const* d_in, const int* in_sizes, int n_in,
                              void* d_out, int out_size, void* d_ws, size_t ws_size,
                              hipStream_t stream) {
    const float* x       = (const float*)d_in[0];
    const float* weight  = (const float*)d_in[1];
    const float* cg_vals = (const float*)d_in[2];
    const int* idx_1     = (const int*)d_in[3];
    const int* idx_2     = (const int*)d_in[4];
    const int* idx_out   = (const int*)d_in[5];
    const int* widx_1    = (const int*)d_in[6];
    const int* widx_2    = (const int*)d_in[7];
    float* y             = (float*)d_out;
    int* ws              = (int*)d_ws;

    const int nnz     = in_sizes[2];
    const int n_atoms = in_sizes[0] / (S9 * NFEAT);       // 32000

    so3_prep_kernel<<<1, THREADS, 0, stream>>>(weight, cg_vals, idx_1, idx_2,
                                               idx_out, widx_1, widx_2, nnz, ws);

    const int total = n_atoms * 32;                        // one thread per (atom, f4)
    so3_main_kernel<<<total / THREADS, THREADS, 0, stream>>>(x, ws, y);
}

// Round 4
// 65.640 us; speedup vs baseline: 1.0145x; 1.0145x over previous
//
#include <hip/hip_runtime.h>

// SO3SelfInteraction: y[a,k,f] = sum_e Wcg[e] * x[a,i1[e],f] * x[a,i2[e],f]
// LMAX=2 -> S=9, N_ATOMS=32000, N_FEAT=128.
//
// R3 changes vs R2:
//  - W padded to [45][12] (48 B rows, 16 B aligned) -> each pair's weights are
//    exactly 3x s_load_dwordx4 instead of 9 scattered s_load_dword (R2 had
//    SGPR_Count=32: no scalar-load pipelining, lgkmcnt stall per pair).
//  - mask/branches removed: straight-line full unroll of all 45 pairs. Scalar
//    loads are unconditional -> scheduler hoists them pairs ahead. Zero-weight
//    FMAs are wasted VALU (~7us device-wide) but we're memory-bound.
//  - f4 vector math (enables v_pk_fma_f32 packed fp32).

#define S9 9
#define NFEAT 128
#define THREADS 256
#define NPAIR 45
#define WSTRIDE 12   // padded floats per pair row

typedef float f4 __attribute__((ext_vector_type(4)));

// d_ws layout: W[45][12] floats (pair-major, zero-padded), at offset 0.

__global__ void so3_prep_kernel(const float* __restrict__ weight,
                                const float* __restrict__ cg_vals,
                                const int* __restrict__ idx_1,
                                const int* __restrict__ idx_2,
                                const int* __restrict__ idx_out,
                                const int* __restrict__ widx_1,
                                const int* __restrict__ widx_2,
                                int nnz, float* __restrict__ W) {
    __shared__ float d[NPAIR * WSTRIDE];
    const int tid = threadIdx.x;

    for (int i = tid; i < NPAIR * WSTRIDE; i += THREADS) d[i] = 0.f;
    __syncthreads();

    for (int e = tid; e < nnz; e += THREADS) {
        const int i = idx_1[e];
        const int j = idx_2[e];
        const int k = idx_out[e];
        const float w = weight[widx_1[e] * 3 + widx_2[e]] * cg_vals[e];
        const int a = min(i, j);
        const int b = max(i, j);
        const int p = a * 9 - a * (a - 1) / 2 + (b - a);
        // <=2 adds per cell ((i,j),(j,i)); fp add commutative -> deterministic
        atomicAdd(&d[p * WSTRIDE + k], w);
    }
    __syncthreads();

    for (int i = tid; i < NPAIR * WSTRIDE; i += THREADS) W[i] = d[i];
}

__global__ __launch_bounds__(THREADS) void so3_main_kernel(
        const float* __restrict__ x,
        const float* __restrict__ W,
        float* __restrict__ y) {
    // pair p -> (a,b), a<=b, compile-time after full unroll
    static constexpr int PA[NPAIR] = {
        0,0,0,0,0,0,0,0,0, 1,1,1,1,1,1,1,1, 2,2,2,2,2,2,2,
        3,3,3,3,3,3, 4,4,4,4,4, 5,5,5,5, 6,6,6, 7,7, 8};
    static constexpr int PB[NPAIR] = {
        0,1,2,3,4,5,6,7,8, 1,2,3,4,5,6,7,8, 2,3,4,5,6,7,8,
        3,4,5,6,7,8, 4,5,6,7,8, 5,6,7,8, 6,7,8, 7,8, 8};

    const int gid  = blockIdx.x * THREADS + threadIdx.x;
    const int atom = gid >> 5;
    const int c4   = gid & 31;
    const size_t base = (size_t)atom * (S9 * NFEAT) + (size_t)c4 * 4;

    f4 xv[S9];
    #pragma unroll
    for (int s = 0; s < S9; ++s)
        xv[s] = *(const f4*)(x + base + (size_t)s * NFEAT);

    f4 acc[S9];
    #pragma unroll
    for (int k = 0; k < S9; ++k) acc[k] = (f4)0.f;

    #pragma unroll
    for (int p = 0; p < NPAIR; ++p) {
        const f4 wA = *(const f4*)(W + p * WSTRIDE);       // k = 0..3
        const f4 wB = *(const f4*)(W + p * WSTRIDE + 4);   // k = 4..7
        const f4 wC = *(const f4*)(W + p * WSTRIDE + 8);   // k = 8 (+pad)
        const f4 prod = xv[PA[p]] * xv[PB[p]];
        acc[0] = acc[0] + wA[0] * prod;
        acc[1] = acc[1] + wA[1] * prod;
        acc[2] = acc[2] + wA[2] * prod;
        acc[3] = acc[3] + wA[3] * prod;
        acc[4] = acc[4] + wB[0] * prod;
        acc[5] = acc[5] + wB[1] * prod;
        acc[6] = acc[6] + wB[2] * prod;
        acc[7] = acc[7] + wB[3] * prod;
        acc[8] = acc[8] + wC[0] * prod;
    }

    #pragma unroll
    for (int k = 0; k < S9; ++k)
        __builtin_nontemporal_store(acc[k], (f4*)(y + base + (size_t)k * NFEAT));
}

extern "C" void kernel_launch(void* const* d_in, const int* in_sizes, int n_in,
                              void* d_out, int out_size, void* d_ws, size_t ws_size,
                              hipStream_t stream) {
    const float* x       = (const float*)d_in[0];
    const float* weight  = (const float*)d_in[1];
    const float* cg_vals = (const float*)d_in[2];
    const int* idx_1     = (const int*)d_in[3];
    const int* idx_2     = (const int*)d_in[4];
    const int* idx_out   = (const int*)d_in[5];
    const int* widx_1    = (const int*)d_in[6];
    const int* widx_2    = (const int*)d_in[7];
    float* y             = (float*)d_out;
    float* W             = (float*)d_ws;

    const int nnz     = in_sizes[2];
    const int n_atoms = in_sizes[0] / (S9 * NFEAT);       // 32000

    so3_prep_kernel<<<1, THREADS, 0, stream>>>(weight, cg_vals, idx_1, idx_2,
                                               idx_out, widx_1, widx_2, nnz, W);

    const int total = n_atoms * 32;                        // one thread per (atom, f4)
    so3_main_kernel<<<total / THREADS, THREADS, 0, stream>>>(x, W, y);
}